// Round 1
// baseline (64.556 us; speedup 1.0000x reference)
//
#include <hip/hip_runtime.h>
#include <hip/hip_bf16.h>

#define NATOM 4096
#define NH 8
#define DIMD 64
#define BLK 128
#define NROW 32
#define BPS 4
#define ROWSTRIDE (NH * DIMD)   // 512 floats
#define SCALE 0.125f
#define L2E 1.4426950408889634f

#define K_LD 72     // [128][72] shorts, row stride 144B (16B aligned, 2-way banks)
#define V_LD 136    // [64][136] shorts (transposed V), row stride 272B
#define P_LD 136    // per-wave [16][136]

typedef __attribute__((ext_vector_type(8))) short bf16x8;
typedef __attribute__((ext_vector_type(4))) float f32x4;

__device__ __forceinline__ short f2bf(float x) {
    unsigned int u = __builtin_bit_cast(unsigned int, x);
    unsigned int r = (u + 0x7fffu + ((u >> 16) & 1u)) >> 16;
    return (short)r;
}

extern "C" __global__ __launch_bounds__(512)
void bsattn_kernel(const float* __restrict__ q,
                   const float* __restrict__ k,
                   const float* __restrict__ v,
                   float* __restrict__ out)
{
    __shared__ short Ksh[BLK * K_LD];      // K block, row-major bf16
    __shared__ short Vsh[DIMD * V_LD];     // V block, transposed bf16
    __shared__ short Psh[8][16 * P_LD];    // per-wave P transpose buffer

    const int r = blockIdx.x;      // query row-block
    const int h = blockIdx.y;      // head
    const int t = threadIdx.x;
    const int w = t >> 6;          // wave 0..7
    const int lane = t & 63;
    const int lr = lane >> 4;      // 0..3
    const int lc = lane & 15;      // 0..15

    // staging maps
    const int krow = t >> 4;           // 0..31 (K rows per iter)
    const int kcol = (t & 15) * 4;     // 0..60
    const int vd  = t & 63;            // d for V-transpose staging
    const int vkg = t >> 6;            // key group 0..7

    // ---- Q fragments, held in registers for the whole kernel ----
    const int qrow_l = w * 16 + lc;
    const float* qp = q + (size_t)(r * BLK + qrow_l) * ROWSTRIDE + h * DIMD + lr * 8;
    bf16x8 qf[2];
    #pragma unroll
    for (int kc = 0; kc < 2; ++kc) {
        float4 a = *(const float4*)(qp + kc * 32);
        float4 b = *(const float4*)(qp + kc * 32 + 4);
        bf16x8 f;
        f[0] = f2bf(a.x); f[1] = f2bf(a.y); f[2] = f2bf(a.z); f[3] = f2bf(a.w);
        f[4] = f2bf(b.x); f[5] = f2bf(b.y); f[6] = f2bf(b.z); f[7] = f2bf(b.w);
        qf[kc] = f;
    }

    f32x4 acc[4] = {};               // O accumulators, [dn] -> 16 cols each
    float m_run[4], l_run[4];
    #pragma unroll
    for (int i = 0; i < 4; ++i) { m_run[i] = -1e30f; l_run[i] = 0.0f; }

    const int kb0 = (r - BPS > 0) ? (r - BPS) : 0;
    const int kb1 = (r + BPS < NROW - 1) ? (r + BPS) : (NROW - 1);

    for (int kb = kb0; kb <= kb1; ++kb) {
        __syncthreads();   // previous tile fully consumed before restage
        const float* kp = k + (size_t)(kb * BLK) * ROWSTRIDE + h * DIMD;
        const float* vp = v + (size_t)(kb * BLK) * ROWSTRIDE + h * DIMD;

        #pragma unroll
        for (int i = 0; i < 4; ++i) {
            // K: row-major float4 load -> bf16 short4 LDS write
            float4 kv = *(const float4*)(kp + (size_t)(i * 32 + krow) * ROWSTRIDE + kcol);
            short4 ks;
            ks.x = f2bf(kv.x); ks.y = f2bf(kv.y); ks.z = f2bf(kv.z); ks.w = f2bf(kv.w);
            *(short4*)&Ksh[(i * 32 + krow) * K_LD + kcol] = ks;

            // V: 4 rows of one d column -> contiguous shorts in transposed tile
            const float* vr = vp + (size_t)(i * 32 + vkg * 4) * ROWSTRIDE + vd;
            short4 vs;
            vs.x = f2bf(vr[0 * ROWSTRIDE]);
            vs.y = f2bf(vr[1 * ROWSTRIDE]);
            vs.z = f2bf(vr[2 * ROWSTRIDE]);
            vs.w = f2bf(vr[3 * ROWSTRIDE]);
            *(short4*)&Vsh[vd * V_LD + i * 32 + vkg * 4] = vs;
        }
        __syncthreads();

        // ---- S = (Q K^T) * scale : 8 n-tiles of 16 keys ----
        f32x4 s[8];
        #pragma unroll
        for (int n = 0; n < 8; ++n) {
            f32x4 z = {};
            #pragma unroll
            for (int kc = 0; kc < 2; ++kc) {
                bf16x8 kf = *(const bf16x8*)&Ksh[(n * 16 + lc) * K_LD + kc * 32 + lr * 8];
                z = __builtin_amdgcn_mfma_f32_16x16x32_bf16(qf[kc], kf, z, 0, 0, 0);
            }
            s[n] = z * SCALE;
        }

        // ---- online softmax, 4 rows per lane ----
        #pragma unroll
        for (int rr = 0; rr < 4; ++rr) {
            float mx = s[0][rr];
            #pragma unroll
            for (int n = 1; n < 8; ++n) mx = fmaxf(mx, s[n][rr]);
            #pragma unroll
            for (int off = 1; off < 16; off <<= 1)
                mx = fmaxf(mx, __shfl_xor(mx, off, 64));
            float mnew = fmaxf(m_run[rr], mx);
            float al = exp2f((m_run[rr] - mnew) * L2E);
            m_run[rr] = mnew;
            float sum = 0.0f;
            #pragma unroll
            for (int n = 0; n < 8; ++n) {
                float p = exp2f((s[n][rr] - mnew) * L2E);
                s[n][rr] = p;
                sum += p;
            }
            #pragma unroll
            for (int off = 1; off < 16; off <<= 1)
                sum += __shfl_xor(sum, off, 64);
            l_run[rr] = l_run[rr] * al + sum;
            #pragma unroll
            for (int dn = 0; dn < 4; ++dn) acc[dn][rr] *= al;
        }

        // ---- P -> LDS (bf16), wave-private transpose ----
        short* pw = &Psh[w][0];
        #pragma unroll
        for (int n = 0; n < 8; ++n) {
            #pragma unroll
            for (int rr = 0; rr < 4; ++rr) {
                pw[(lr * 4 + rr) * P_LD + n * 16 + lc] = f2bf(s[n][rr]);
            }
        }

        // ---- O += P V ----
        #pragma unroll
        for (int dn = 0; dn < 4; ++dn) {
            f32x4 o = acc[dn];
            #pragma unroll
            for (int kc = 0; kc < 4; ++kc) {
                bf16x8 pf = *(const bf16x8*)&pw[lc * P_LD + kc * 32 + lr * 8];
                bf16x8 vf = *(const bf16x8*)&Vsh[(dn * 16 + lc) * V_LD + kc * 32 + lr * 8];
                o = __builtin_amdgcn_mfma_f32_16x16x32_bf16(pf, vf, o, 0, 0, 0);
            }
            acc[dn] = o;
        }
    }

    // ---- epilogue: normalize and store ----
    float* op = out + (size_t)(r * BLK + w * 16) * ROWSTRIDE + h * DIMD;
    #pragma unroll
    for (int rr = 0; rr < 4; ++rr) {
        float inv = 1.0f / l_run[rr];
        float* orow = op + (size_t)(lr * 4 + rr) * ROWSTRIDE;
        #pragma unroll
        for (int dn = 0; dn < 4; ++dn) {
            orow[dn * 16 + lc] = acc[dn][rr] * inv;
        }
    }
}

extern "C" void kernel_launch(void* const* d_in, const int* in_sizes, int n_in,
                              void* d_out, int out_size, void* d_ws, size_t ws_size,
                              hipStream_t stream) {
    const float* q = (const float*)d_in[0];
    const float* k = (const float*)d_in[1];
    const float* v = (const float*)d_in[2];
    float* out = (float*)d_out;
    dim3 grid(NROW, NH);
    bsattn_kernel<<<grid, 512, 0, stream>>>(q, k, v, out);
}

// Round 2
// 53.703 us; speedup vs baseline: 1.2021x; 1.2021x over previous
//
#include <hip/hip_runtime.h>
#include <hip/hip_bf16.h>

#define NATOM 4096
#define NH 8
#define DIMD 64
#define BLK 128
#define NROW 32
#define BPS 4
#define ROWSTRIDE (NH * DIMD)   // 512 floats
#define SCALE 0.125f
#define L2E 1.4426950408889634f

#define K_LD 72     // [128][72] shorts, row stride 144B (16B aligned)
#define V_LD 136    // [64][136] shorts (transposed V), row stride 272B
#define P_LD 136    // per-wave [16][136]

#define HEAD_ELEMS (NATOM * DIMD)          // 262144 elems per head (bf16 planes)
#define WS_NEEDED  (2u * NH * HEAD_ELEMS * 2u)   // Kb + Vt, bf16

typedef __attribute__((ext_vector_type(8))) short bf16x8;
typedef __attribute__((ext_vector_type(4))) float f32x4;

__device__ __forceinline__ short f2bf(float x) {
    unsigned int u = __builtin_bit_cast(unsigned int, x);
    unsigned int r = (u + 0x7fffu + ((u >> 16) & 1u)) >> 16;
    return (short)r;
}

// ---------------- pre-kernel 1: K fp32 [n][h][d] -> bf16 [h][n][d] ----------------
extern "C" __global__ __launch_bounds__(256)
void conv_k_kernel(const float* __restrict__ k, short* __restrict__ Kb)
{
    int tid = blockIdx.x * 256 + threadIdx.x;   // 262144 threads, 8 elems each
    int h   = tid >> 15;                        // 32768 slots per head
    int rem = tid & 32767;
    int n   = rem >> 3;
    int d0  = (rem & 7) * 8;
    const float* src = k + (size_t)n * ROWSTRIDE + h * DIMD + d0;
    float4 a = *(const float4*)src;
    float4 b = *(const float4*)(src + 4);
    bf16x8 f;
    f[0] = f2bf(a.x); f[1] = f2bf(a.y); f[2] = f2bf(a.z); f[3] = f2bf(a.w);
    f[4] = f2bf(b.x); f[5] = f2bf(b.y); f[6] = f2bf(b.z); f[7] = f2bf(b.w);
    *(bf16x8*)(Kb + (size_t)h * HEAD_ELEMS + (size_t)n * DIMD + d0) = f;
}

// ------------- pre-kernel 2: V fp32 [n][h][d] -> bf16 transposed [h][d][n] -------------
extern "C" __global__ __launch_bounds__(256)
void trans_v_kernel(const float* __restrict__ v, short* __restrict__ Vt)
{
    __shared__ short Tr[DIMD * V_LD];
    const int nb = blockIdx.x;    // 128-key tile
    const int h  = blockIdx.y;
    const int t  = threadIdx.x;
    const int vd = t & 63;
    const int g  = t >> 6;        // 0..3

    const float* vp = v + (size_t)(nb * BLK) * ROWSTRIDE + h * DIMD + vd;
    #pragma unroll
    for (int i = 0; i < 8; ++i) {
        int n4 = i * 16 + g * 4;
        const float* vr = vp + (size_t)n4 * ROWSTRIDE;
        short4 s4;
        s4.x = f2bf(vr[0 * ROWSTRIDE]);
        s4.y = f2bf(vr[1 * ROWSTRIDE]);
        s4.z = f2bf(vr[2 * ROWSTRIDE]);
        s4.w = f2bf(vr[3 * ROWSTRIDE]);
        *(short4*)&Tr[vd * V_LD + n4] = s4;
    }
    __syncthreads();
    #pragma unroll
    for (int i = 0; i < 4; ++i) {
        int s  = i * 256 + t;
        int d  = s >> 4;
        int c8 = (s & 15) * 8;
        *(bf16x8*)(Vt + (size_t)h * HEAD_ELEMS + (size_t)d * NATOM + nb * BLK + c8) =
            *(const bf16x8*)&Tr[d * V_LD + c8];
    }
}

// ---------------- main kernel: 256 thr (4 waves), 64 query rows per block ----------------
extern "C" __global__ __launch_bounds__(256)
void bsattn_main(const float* __restrict__ q,
                 const short* __restrict__ Kb,
                 const short* __restrict__ Vt,
                 float* __restrict__ out)
{
    __shared__ short Ksh[BLK * K_LD];
    __shared__ short Vsh[DIMD * V_LD];
    __shared__ short Psh[4][16 * P_LD];

    const int br = blockIdx.x;        // 64-row query block, 0..63
    const int h  = blockIdx.y;
    const int r  = br >> 1;           // 128-row band block
    const int t  = threadIdx.x;
    const int w  = t >> 6;            // wave 0..3
    const int lane = t & 63;
    const int lr = lane >> 4;
    const int lc = lane & 15;

    // ---- Q fragments (scale folded in) ----
    const int qrow = br * 64 + w * 16 + lc;
    const float* qp = q + (size_t)qrow * ROWSTRIDE + h * DIMD + lr * 8;
    bf16x8 qf[2];
    #pragma unroll
    for (int kc = 0; kc < 2; ++kc) {
        float4 a = *(const float4*)(qp + kc * 32);
        float4 b = *(const float4*)(qp + kc * 32 + 4);
        bf16x8 f;
        f[0] = f2bf(a.x * SCALE); f[1] = f2bf(a.y * SCALE);
        f[2] = f2bf(a.z * SCALE); f[3] = f2bf(a.w * SCALE);
        f[4] = f2bf(b.x * SCALE); f[5] = f2bf(b.y * SCALE);
        f[6] = f2bf(b.z * SCALE); f[7] = f2bf(b.w * SCALE);
        qf[kc] = f;
    }

    const short* kbase = Kb + (size_t)h * HEAD_ELEMS;
    const short* vbase = Vt + (size_t)h * HEAD_ELEMS;

    f32x4 acc[4] = {};
    float m_run[4], l_run[4];
    #pragma unroll
    for (int i = 0; i < 4; ++i) { m_run[i] = -1e30f; l_run[i] = 0.0f; }

    const int kb0 = (r - BPS > 0) ? (r - BPS) : 0;
    const int kb1 = (r + BPS < NROW - 1) ? (r + BPS) : (NROW - 1);

    bf16x8 kpre[4], vpre[4];
    {   // prologue prefetch
        const short* kg = kbase + (size_t)kb0 * BLK * DIMD;
        const short* vg = vbase + (size_t)kb0 * BLK;
        #pragma unroll
        for (int i = 0; i < 4; ++i) {
            int s = i * 256 + t;
            kpre[i] = *(const bf16x8*)(kg + (size_t)(s >> 3) * DIMD + (s & 7) * 8);
            vpre[i] = *(const bf16x8*)(vg + (size_t)(s >> 4) * NATOM + (s & 15) * 8);
        }
    }

    for (int kb = kb0; kb <= kb1; ++kb) {
        __syncthreads();   // previous tile fully consumed
        #pragma unroll
        for (int i = 0; i < 4; ++i) {
            int s = i * 256 + t;
            *(bf16x8*)&Ksh[(s >> 3) * K_LD + (s & 7) * 8] = kpre[i];
            *(bf16x8*)&Vsh[(s >> 4) * V_LD + (s & 15) * 8] = vpre[i];
        }
        if (kb < kb1) {    // prefetch next tile; latency hides under compute
            const short* kg = kbase + (size_t)(kb + 1) * BLK * DIMD;
            const short* vg = vbase + (size_t)(kb + 1) * BLK;
            #pragma unroll
            for (int i = 0; i < 4; ++i) {
                int s = i * 256 + t;
                kpre[i] = *(const bf16x8*)(kg + (size_t)(s >> 3) * DIMD + (s & 7) * 8);
                vpre[i] = *(const bf16x8*)(vg + (size_t)(s >> 4) * NATOM + (s & 15) * 8);
            }
        }
        __syncthreads();

        // ---- S = (Q*scale) K^T : 8 n-tiles of 16 keys ----
        f32x4 s[8];
        #pragma unroll
        for (int n = 0; n < 8; ++n) {
            f32x4 z = {};
            #pragma unroll
            for (int kc = 0; kc < 2; ++kc) {
                bf16x8 kf = *(const bf16x8*)&Ksh[(n * 16 + lc) * K_LD + kc * 32 + lr * 8];
                z = __builtin_amdgcn_mfma_f32_16x16x32_bf16(qf[kc], kf, z, 0, 0, 0);
            }
            s[n] = z;
        }

        // ---- online softmax, 4 rows per lane ----
        #pragma unroll
        for (int rr = 0; rr < 4; ++rr) {
            float mx = s[0][rr];
            #pragma unroll
            for (int n = 1; n < 8; ++n) mx = fmaxf(mx, s[n][rr]);
            #pragma unroll
            for (int off = 1; off < 16; off <<= 1)
                mx = fmaxf(mx, __shfl_xor(mx, off, 64));
            float mnew = fmaxf(m_run[rr], mx);
            float al = exp2f((m_run[rr] - mnew) * L2E);
            m_run[rr] = mnew;
            float sum = 0.0f;
            #pragma unroll
            for (int n = 0; n < 8; ++n) {
                float p = exp2f((s[n][rr] - mnew) * L2E);
                s[n][rr] = p;
                sum += p;
            }
            #pragma unroll
            for (int off = 1; off < 16; off <<= 1)
                sum += __shfl_xor(sum, off, 64);
            l_run[rr] = l_run[rr] * al + sum;
            #pragma unroll
            for (int dn = 0; dn < 4; ++dn) acc[dn][rr] *= al;
        }

        // ---- P -> LDS (bf16), wave-private transpose ----
        short* pw = &Psh[w][0];
        #pragma unroll
        for (int n = 0; n < 8; ++n) {
            #pragma unroll
            for (int rr = 0; rr < 4; ++rr) {
                pw[(lr * 4 + rr) * P_LD + n * 16 + lc] = f2bf(s[n][rr]);
            }
        }

        // ---- O += P V ----
        #pragma unroll
        for (int dn = 0; dn < 4; ++dn) {
            f32x4 o = acc[dn];
            #pragma unroll
            for (int kc = 0; kc < 4; ++kc) {
                bf16x8 pf = *(const bf16x8*)&pw[lc * P_LD + kc * 32 + lr * 8];
                bf16x8 vf = *(const bf16x8*)&Vsh[(dn * 16 + lc) * V_LD + kc * 32 + lr * 8];
                o = __builtin_amdgcn_mfma_f32_16x16x32_bf16(pf, vf, o, 0, 0, 0);
            }
            acc[dn] = o;
        }
    }

    // ---- epilogue ----
    float* op = out + (size_t)(br * 64 + w * 16) * ROWSTRIDE + h * DIMD;
    #pragma unroll
    for (int rr = 0; rr < 4; ++rr) {
        float inv = 1.0f / l_run[rr];
        float* orow = op + (size_t)(lr * 4 + rr) * ROWSTRIDE;
        #pragma unroll
        for (int dn = 0; dn < 4; ++dn) {
            orow[dn * 16 + lc] = acc[dn][rr] * inv;
        }
    }
}

// ---------------- fallback (round-1 kernel, fp32 direct) ----------------
extern "C" __global__ __launch_bounds__(512)
void bsattn_fallback(const float* __restrict__ q,
                     const float* __restrict__ k,
                     const float* __restrict__ v,
                     float* __restrict__ out)
{
    __shared__ short Ksh[BLK * K_LD];
    __shared__ short Vsh[DIMD * V_LD];
    __shared__ short Psh[8][16 * P_LD];

    const int r = blockIdx.x;
    const int h = blockIdx.y;
    const int t = threadIdx.x;
    const int w = t >> 6;
    const int lane = t & 63;
    const int lr = lane >> 4;
    const int lc = lane & 15;

    const int krow = t >> 4;
    const int kcol = (t & 15) * 4;
    const int vd  = t & 63;
    const int vkg = t >> 6;

    const int qrow_l = w * 16 + lc;
    const float* qp = q + (size_t)(r * BLK + qrow_l) * ROWSTRIDE + h * DIMD + lr * 8;
    bf16x8 qf[2];
    #pragma unroll
    for (int kc = 0; kc < 2; ++kc) {
        float4 a = *(const float4*)(qp + kc * 32);
        float4 b = *(const float4*)(qp + kc * 32 + 4);
        bf16x8 f;
        f[0] = f2bf(a.x); f[1] = f2bf(a.y); f[2] = f2bf(a.z); f[3] = f2bf(a.w);
        f[4] = f2bf(b.x); f[5] = f2bf(b.y); f[6] = f2bf(b.z); f[7] = f2bf(b.w);
        qf[kc] = f;
    }

    f32x4 acc[4] = {};
    float m_run[4], l_run[4];
    #pragma unroll
    for (int i = 0; i < 4; ++i) { m_run[i] = -1e30f; l_run[i] = 0.0f; }

    const int kb0 = (r - BPS > 0) ? (r - BPS) : 0;
    const int kb1 = (r + BPS < NROW - 1) ? (r + BPS) : (NROW - 1);

    for (int kb = kb0; kb <= kb1; ++kb) {
        __syncthreads();
        const float* kp = k + (size_t)(kb * BLK) * ROWSTRIDE + h * DIMD;
        const float* vp = v + (size_t)(kb * BLK) * ROWSTRIDE + h * DIMD;

        #pragma unroll
        for (int i = 0; i < 4; ++i) {
            float4 kv = *(const float4*)(kp + (size_t)(i * 32 + krow) * ROWSTRIDE + kcol);
            short4 ks;
            ks.x = f2bf(kv.x); ks.y = f2bf(kv.y); ks.z = f2bf(kv.z); ks.w = f2bf(kv.w);
            *(short4*)&Ksh[(i * 32 + krow) * K_LD + kcol] = ks;

            const float* vr = vp + (size_t)(i * 32 + vkg * 4) * ROWSTRIDE + vd;
            short4 vs;
            vs.x = f2bf(vr[0 * ROWSTRIDE]);
            vs.y = f2bf(vr[1 * ROWSTRIDE]);
            vs.z = f2bf(vr[2 * ROWSTRIDE]);
            vs.w = f2bf(vr[3 * ROWSTRIDE]);
            *(short4*)&Vsh[vd * V_LD + i * 32 + vkg * 4] = vs;
        }
        __syncthreads();

        f32x4 s[8];
        #pragma unroll
        for (int n = 0; n < 8; ++n) {
            f32x4 z = {};
            #pragma unroll
            for (int kc = 0; kc < 2; ++kc) {
                bf16x8 kf = *(const bf16x8*)&Ksh[(n * 16 + lc) * K_LD + kc * 32 + lr * 8];
                z = __builtin_amdgcn_mfma_f32_16x16x32_bf16(qf[kc], kf, z, 0, 0, 0);
            }
            s[n] = z * SCALE;
        }

        #pragma unroll
        for (int rr = 0; rr < 4; ++rr) {
            float mx = s[0][rr];
            #pragma unroll
            for (int n = 1; n < 8; ++n) mx = fmaxf(mx, s[n][rr]);
            #pragma unroll
            for (int off = 1; off < 16; off <<= 1)
                mx = fmaxf(mx, __shfl_xor(mx, off, 64));
            float mnew = fmaxf(m_run[rr], mx);
            float al = exp2f((m_run[rr] - mnew) * L2E);
            m_run[rr] = mnew;
            float sum = 0.0f;
            #pragma unroll
            for (int n = 0; n < 8; ++n) {
                float p = exp2f((s[n][rr] - mnew) * L2E);
                s[n][rr] = p;
                sum += p;
            }
            #pragma unroll
            for (int off = 1; off < 16; off <<= 1)
                sum += __shfl_xor(sum, off, 64);
            l_run[rr] = l_run[rr] * al + sum;
            #pragma unroll
            for (int dn = 0; dn < 4; ++dn) acc[dn][rr] *= al;
        }

        short* pw = &Psh[w][0];
        #pragma unroll
        for (int n = 0; n < 8; ++n) {
            #pragma unroll
            for (int rr = 0; rr < 4; ++rr) {
                pw[(lr * 4 + rr) * P_LD + n * 16 + lc] = f2bf(s[n][rr]);
            }
        }

        #pragma unroll
        for (int dn = 0; dn < 4; ++dn) {
            f32x4 o = acc[dn];
            #pragma unroll
            for (int kc = 0; kc < 4; ++kc) {
                bf16x8 pf = *(const bf16x8*)&pw[lc * P_LD + kc * 32 + lr * 8];
                bf16x8 vf = *(const bf16x8*)&Vsh[(dn * 16 + lc) * V_LD + kc * 32 + lr * 8];
                o = __builtin_amdgcn_mfma_f32_16x16x32_bf16(pf, vf, o, 0, 0, 0);
            }
            acc[dn] = o;
        }
    }

    float* op = out + (size_t)(r * BLK + w * 16) * ROWSTRIDE + h * DIMD;
    #pragma unroll
    for (int rr = 0; rr < 4; ++rr) {
        float inv = 1.0f / l_run[rr];
        float* orow = op + (size_t)(lr * 4 + rr) * ROWSTRIDE;
        #pragma unroll
        for (int dn = 0; dn < 4; ++dn) {
            orow[dn * 16 + lc] = acc[dn][rr] * inv;
        }
    }
}

extern "C" void kernel_launch(void* const* d_in, const int* in_sizes, int n_in,
                              void* d_out, int out_size, void* d_ws, size_t ws_size,
                              hipStream_t stream) {
    const float* q = (const float*)d_in[0];
    const float* k = (const float*)d_in[1];
    const float* v = (const float*)d_in[2];
    float* out = (float*)d_out;

    if (ws_size >= (size_t)WS_NEEDED) {
        short* Kb = (short*)d_ws;
        short* Vt = Kb + (size_t)NH * HEAD_ELEMS;
        conv_k_kernel<<<1024, 256, 0, stream>>>(k, Kb);
        trans_v_kernel<<<dim3(NROW, NH), 256, 0, stream>>>(v, Vt);
        bsattn_main<<<dim3(NROW * 2, NH), 256, 0, stream>>>(q, Kb, Vt, out);
    } else {
        bsattn_fallback<<<dim3(NROW, NH), 512, 0, stream>>>(q, k, v, out);
    }
}

// Round 3
// 44.468 us; speedup vs baseline: 1.4518x; 1.2077x over previous
//
#include <hip/hip_runtime.h>
#include <hip/hip_bf16.h>

#define NATOM 4096
#define NH 8
#define DIMD 64
#define BLK 128
#define NROW 32
#define BPS 4
#define ROWSTRIDE (NH * DIMD)   // 512 floats
#define SCALE 0.125f
#define L2E 1.4426950408889634f

#define K_LD 72     // [128][72] shorts, row stride 144B
#define V_LD 136    // [64][136] shorts (transposed V)
#define P_LD 136    // per-wave [16][136]

#define HEAD_ELEMS (NATOM * DIMD)               // 262144 bf16 per head plane
#define WS_NEEDED  (2u * NH * HEAD_ELEMS * 2u)  // Kb + Vt, bf16

typedef __attribute__((ext_vector_type(8))) short bf16x8;
typedef __attribute__((ext_vector_type(4))) float f32x4;

__device__ __forceinline__ short f2bf(float x) {
    unsigned int u = __builtin_bit_cast(unsigned int, x);
    unsigned int r = (u + 0x7fffu + ((u >> 16) & 1u)) >> 16;
    return (short)r;
}
__device__ __forceinline__ f32x4 vmax4(f32x4 a, f32x4 b) {
    f32x4 r;
    r[0] = fmaxf(a[0], b[0]); r[1] = fmaxf(a[1], b[1]);
    r[2] = fmaxf(a[2], b[2]); r[3] = fmaxf(a[3], b[3]);
    return r;
}

// ---------------- prep kernel: K -> bf16 [h][n][d]; V -> bf16 [h][d][n] ----------------
extern "C" __global__ __launch_bounds__(256)
void prep_kernel(const float* __restrict__ k, const float* __restrict__ v,
                 short* __restrict__ Kb, short* __restrict__ Vt)
{
    __shared__ short Tr[DIMD * V_LD];
    const int b = blockIdx.x;
    const int t = threadIdx.x;
    if (b < 1024) {
        // K convert: 262144 slots of 8 elems
        int tid = b * 256 + t;
        int h   = tid >> 15;
        int rem = tid & 32767;
        int n   = rem >> 3;
        int d0  = (rem & 7) * 8;
        const float* src = k + (size_t)n * ROWSTRIDE + h * DIMD + d0;
        float4 a = *(const float4*)src;
        float4 c = *(const float4*)(src + 4);
        bf16x8 f;
        f[0] = f2bf(a.x); f[1] = f2bf(a.y); f[2] = f2bf(a.z); f[3] = f2bf(a.w);
        f[4] = f2bf(c.x); f[5] = f2bf(c.y); f[6] = f2bf(c.z); f[7] = f2bf(c.w);
        *(bf16x8*)(Kb + (size_t)h * HEAD_ELEMS + (size_t)n * DIMD + d0) = f;
    } else {
        // V transpose: 256 tiles (nb, h)
        int bb = b - 1024;
        int nb = bb & 31;
        int h  = bb >> 5;
        const int vd = t & 63;
        const int g  = t >> 6;
        const float* vp = v + (size_t)(nb * BLK) * ROWSTRIDE + h * DIMD + vd;
        #pragma unroll
        for (int i = 0; i < 8; ++i) {
            int n4 = i * 16 + g * 4;
            const float* vr = vp + (size_t)n4 * ROWSTRIDE;
            short4 s4;
            s4.x = f2bf(vr[0 * ROWSTRIDE]);
            s4.y = f2bf(vr[1 * ROWSTRIDE]);
            s4.z = f2bf(vr[2 * ROWSTRIDE]);
            s4.w = f2bf(vr[3 * ROWSTRIDE]);
            *(short4*)&Tr[vd * V_LD + n4] = s4;
        }
        __syncthreads();
        #pragma unroll
        for (int i = 0; i < 4; ++i) {
            int s  = i * 256 + t;
            int d  = s >> 4;
            int c8 = (s & 15) * 8;
            *(bf16x8*)(Vt + (size_t)h * HEAD_ELEMS + (size_t)d * NATOM + nb * BLK + c8) =
                *(const bf16x8*)&Tr[d * V_LD + c8];
        }
    }
}

// ---------------- main kernel: swapped-operand flash attention ----------------
// S^T = mfma(K,Q): lane holds S[key = mt*16 + lr*4 + reg][q = lc]
// O^T = mfma(Vt,P): lane holds O[q = lc][d = dn*16 + lr*4 + reg]
extern "C" __global__ __launch_bounds__(256)
void bsattn_main(const float* __restrict__ q,
                 const short* __restrict__ Kb,
                 const short* __restrict__ Vt,
                 float* __restrict__ out)
{
    __shared__ short Ksh[BLK * K_LD];
    __shared__ short Vsh[DIMD * V_LD];
    __shared__ short Psh[4][16 * P_LD];

    const int br = blockIdx.x;        // 64-row query block, 0..63
    const int h  = blockIdx.y;
    const int r  = br >> 1;           // 128-row band block
    const int t  = threadIdx.x;
    const int w  = t >> 6;
    const int lane = t & 63;
    const int lr = lane >> 4;
    const int lc = lane & 15;

    // ---- Q fragments (scale folded in); B-operand layout: q = lc, d = kc*32 + lr*8 + j ----
    const int qbase = br * 64 + w * 16;
    const float* qp = q + (size_t)(qbase + lc) * ROWSTRIDE + h * DIMD + lr * 8;
    bf16x8 qf[2];
    #pragma unroll
    for (int kc = 0; kc < 2; ++kc) {
        float4 a = *(const float4*)(qp + kc * 32);
        float4 b = *(const float4*)(qp + kc * 32 + 4);
        bf16x8 f;
        f[0] = f2bf(a.x * SCALE); f[1] = f2bf(a.y * SCALE);
        f[2] = f2bf(a.z * SCALE); f[3] = f2bf(a.w * SCALE);
        f[4] = f2bf(b.x * SCALE); f[5] = f2bf(b.y * SCALE);
        f[6] = f2bf(b.z * SCALE); f[7] = f2bf(b.w * SCALE);
        qf[kc] = f;
    }

    const short* kbase = Kb + (size_t)h * HEAD_ELEMS;
    const short* vbase = Vt + (size_t)h * HEAD_ELEMS;

    f32x4 acc[4] = {};
    float m_run = -1e30f, l_run = 0.0f;

    const int kb0 = (r - BPS > 0) ? (r - BPS) : 0;
    const int kb1 = (r + BPS < NROW - 1) ? (r + BPS) : (NROW - 1);

    bf16x8 kpre[4], vpre[4];
    {   // prologue prefetch
        const short* kg = kbase + (size_t)kb0 * BLK * DIMD;
        const short* vg = vbase + (size_t)kb0 * BLK;
        #pragma unroll
        for (int i = 0; i < 4; ++i) {
            int s = i * 256 + t;
            kpre[i] = *(const bf16x8*)(kg + (size_t)(s >> 3) * DIMD + (s & 7) * 8);
            vpre[i] = *(const bf16x8*)(vg + (size_t)(s >> 4) * NATOM + (s & 15) * 8);
        }
    }

    for (int kb = kb0; kb <= kb1; ++kb) {
        __syncthreads();   // previous tile fully consumed
        #pragma unroll
        for (int i = 0; i < 4; ++i) {
            int s = i * 256 + t;
            *(bf16x8*)&Ksh[(s >> 3) * K_LD + (s & 7) * 8] = kpre[i];
            *(bf16x8*)&Vsh[(s >> 4) * V_LD + (s & 15) * 8] = vpre[i];
        }
        if (kb < kb1) {    // prefetch next tile; latency hides under compute
            const short* kg = kbase + (size_t)(kb + 1) * BLK * DIMD;
            const short* vg = vbase + (size_t)(kb + 1) * BLK;
            #pragma unroll
            for (int i = 0; i < 4; ++i) {
                int s = i * 256 + t;
                kpre[i] = *(const bf16x8*)(kg + (size_t)(s >> 3) * DIMD + (s & 7) * 8);
                vpre[i] = *(const bf16x8*)(vg + (size_t)(s >> 4) * NATOM + (s & 15) * 8);
            }
        }
        __syncthreads();

        // ---- S^T = K (Q*scale)^T : 8 m-tiles of 16 keys; A = K frag, B = Q frag ----
        f32x4 s[8];
        #pragma unroll
        for (int mt = 0; mt < 8; ++mt) {
            f32x4 z = {};
            #pragma unroll
            for (int kc = 0; kc < 2; ++kc) {
                bf16x8 kf = *(const bf16x8*)&Ksh[(mt * 16 + lc) * K_LD + kc * 32 + lr * 8];
                z = __builtin_amdgcn_mfma_f32_16x16x32_bf16(kf, qf[kc], z, 0, 0, 0);
            }
            s[mt] = z;
        }

        // ---- online softmax: keys lane-local, only 2+2 shuffles ----
        f32x4 a0 = vmax4(s[0], s[1]), a1 = vmax4(s[2], s[3]);
        f32x4 a2 = vmax4(s[4], s[5]), a3 = vmax4(s[6], s[7]);
        a0 = vmax4(vmax4(a0, a1), vmax4(a2, a3));
        float mx = fmaxf(fmaxf(a0[0], a0[1]), fmaxf(a0[2], a0[3]));
        mx = fmaxf(mx, __shfl_xor(mx, 16, 64));
        mx = fmaxf(mx, __shfl_xor(mx, 32, 64));
        float mnew = fmaxf(m_run, mx);
        float al = exp2f((m_run - mnew) * L2E);
        m_run = mnew;

        f32x4 sv = {};
        #pragma unroll
        for (int mt = 0; mt < 8; ++mt) {
            f32x4 p;
            #pragma unroll
            for (int e = 0; e < 4; ++e) p[e] = exp2f((s[mt][e] - mnew) * L2E);
            s[mt] = p;
            sv[0] += p[0]; sv[1] += p[1]; sv[2] += p[2]; sv[3] += p[3];
        }
        float sum = (sv[0] + sv[1]) + (sv[2] + sv[3]);
        sum += __shfl_xor(sum, 16, 64);
        sum += __shfl_xor(sum, 32, 64);
        l_run = l_run * al + sum;
        #pragma unroll
        for (int dn = 0; dn < 4; ++dn) {
            acc[dn][0] *= al; acc[dn][1] *= al; acc[dn][2] *= al; acc[dn][3] *= al;
        }

        // ---- P -> wave-private LDS: packed short4 writes, rows = query ----
        short* pw = &Psh[w][0];
        #pragma unroll
        for (int mt = 0; mt < 8; ++mt) {
            short4 ps;
            ps.x = f2bf(s[mt][0]); ps.y = f2bf(s[mt][1]);
            ps.z = f2bf(s[mt][2]); ps.w = f2bf(s[mt][3]);
            *(short4*)&pw[lc * P_LD + mt * 16 + lr * 4] = ps;
        }

        // ---- O^T += Vt P : A = Vt frag, B = P frag (hoisted) ----
        bf16x8 pf[4];
        #pragma unroll
        for (int kc = 0; kc < 4; ++kc)
            pf[kc] = *(const bf16x8*)&pw[lc * P_LD + kc * 32 + lr * 8];
        #pragma unroll
        for (int dn = 0; dn < 4; ++dn) {
            f32x4 o = acc[dn];
            #pragma unroll
            for (int kc = 0; kc < 4; ++kc) {
                bf16x8 vf = *(const bf16x8*)&Vsh[(dn * 16 + lc) * V_LD + kc * 32 + lr * 8];
                o = __builtin_amdgcn_mfma_f32_16x16x32_bf16(vf, pf[kc], o, 0, 0, 0);
            }
            acc[dn] = o;
        }
    }

    // ---- epilogue: q = lc per lane, d = dn*16 + lr*4 + reg -> float4 stores ----
    float inv = 1.0f / l_run;
    float* orow = out + (size_t)(qbase + lc) * ROWSTRIDE + h * DIMD;
    #pragma unroll
    for (int dn = 0; dn < 4; ++dn) {
        f32x4 rv;
        rv[0] = acc[dn][0] * inv; rv[1] = acc[dn][1] * inv;
        rv[2] = acc[dn][2] * inv; rv[3] = acc[dn][3] * inv;
        *(float4*)(orow + dn * 16 + lr * 4) = *(float4*)&rv;
    }
}

// ---------------- fallback (fp32 direct, round-1 proven) ----------------
extern "C" __global__ __launch_bounds__(512)
void bsattn_fallback(const float* __restrict__ q,
                     const float* __restrict__ k,
                     const float* __restrict__ v,
                     float* __restrict__ out)
{
    __shared__ short Ksh[BLK * K_LD];
    __shared__ short Vsh[DIMD * V_LD];
    __shared__ short Psh[8][16 * P_LD];

    const int r = blockIdx.x;
    const int h = blockIdx.y;
    const int t = threadIdx.x;
    const int w = t >> 6;
    const int lane = t & 63;
    const int lr = lane >> 4;
    const int lc = lane & 15;

    const int krow = t >> 4;
    const int kcol = (t & 15) * 4;
    const int vd  = t & 63;
    const int vkg = t >> 6;

    const int qrow_l = w * 16 + lc;
    const float* qp = q + (size_t)(r * BLK + qrow_l) * ROWSTRIDE + h * DIMD + lr * 8;
    bf16x8 qf[2];
    #pragma unroll
    for (int kc = 0; kc < 2; ++kc) {
        float4 a = *(const float4*)(qp + kc * 32);
        float4 b = *(const float4*)(qp + kc * 32 + 4);
        bf16x8 f;
        f[0] = f2bf(a.x); f[1] = f2bf(a.y); f[2] = f2bf(a.z); f[3] = f2bf(a.w);
        f[4] = f2bf(b.x); f[5] = f2bf(b.y); f[6] = f2bf(b.z); f[7] = f2bf(b.w);
        qf[kc] = f;
    }

    f32x4 acc[4] = {};
    float m_run[4], l_run[4];
    #pragma unroll
    for (int i = 0; i < 4; ++i) { m_run[i] = -1e30f; l_run[i] = 0.0f; }

    const int kb0 = (r - BPS > 0) ? (r - BPS) : 0;
    const int kb1 = (r + BPS < NROW - 1) ? (r + BPS) : (NROW - 1);

    for (int kb = kb0; kb <= kb1; ++kb) {
        __syncthreads();
        const float* kp = k + (size_t)(kb * BLK) * ROWSTRIDE + h * DIMD;
        const float* vp = v + (size_t)(kb * BLK) * ROWSTRIDE + h * DIMD;

        #pragma unroll
        for (int i = 0; i < 4; ++i) {
            float4 kv = *(const float4*)(kp + (size_t)(i * 32 + krow) * ROWSTRIDE + kcol);
            short4 ks;
            ks.x = f2bf(kv.x); ks.y = f2bf(kv.y); ks.z = f2bf(kv.z); ks.w = f2bf(kv.w);
            *(short4*)&Ksh[(i * 32 + krow) * K_LD + kcol] = ks;

            const float* vr = vp + (size_t)(i * 32 + vkg * 4) * ROWSTRIDE + vd;
            short4 vs;
            vs.x = f2bf(vr[0 * ROWSTRIDE]);
            vs.y = f2bf(vr[1 * ROWSTRIDE]);
            vs.z = f2bf(vr[2 * ROWSTRIDE]);
            vs.w = f2bf(vr[3 * ROWSTRIDE]);
            *(short4*)&Vsh[vd * V_LD + i * 32 + vkg * 4] = vs;
        }
        __syncthreads();

        f32x4 s[8];
        #pragma unroll
        for (int n = 0; n < 8; ++n) {
            f32x4 z = {};
            #pragma unroll
            for (int kc = 0; kc < 2; ++kc) {
                bf16x8 kf = *(const bf16x8*)&Ksh[(n * 16 + lc) * K_LD + kc * 32 + lr * 8];
                z = __builtin_amdgcn_mfma_f32_16x16x32_bf16(qf[kc], kf, z, 0, 0, 0);
            }
            s[n] = z * SCALE;
        }

        #pragma unroll
        for (int rr = 0; rr < 4; ++rr) {
            float mx = s[0][rr];
            #pragma unroll
            for (int n = 1; n < 8; ++n) mx = fmaxf(mx, s[n][rr]);
            #pragma unroll
            for (int off = 1; off < 16; off <<= 1)
                mx = fmaxf(mx, __shfl_xor(mx, off, 64));
            float mnew = fmaxf(m_run[rr], mx);
            float al = exp2f((m_run[rr] - mnew) * L2E);
            m_run[rr] = mnew;
            float sum = 0.0f;
            #pragma unroll
            for (int n = 0; n < 8; ++n) {
                float p = exp2f((s[n][rr] - mnew) * L2E);
                s[n][rr] = p;
                sum += p;
            }
            #pragma unroll
            for (int off = 1; off < 16; off <<= 1)
                sum += __shfl_xor(sum, off, 64);
            l_run[rr] = l_run[rr] * al + sum;
            #pragma unroll
            for (int dn = 0; dn < 4; ++dn) acc[dn][rr] *= al;
        }

        short* pw = &Psh[w][0];
        #pragma unroll
        for (int n = 0; n < 8; ++n) {
            #pragma unroll
            for (int rr = 0; rr < 4; ++rr) {
                pw[(lr * 4 + rr) * P_LD + n * 16 + lc] = f2bf(s[n][rr]);
            }
        }

        #pragma unroll
        for (int dn = 0; dn < 4; ++dn) {
            f32x4 o = acc[dn];
            #pragma unroll
            for (int kc = 0; kc < 4; ++kc) {
                bf16x8 pf = *(const bf16x8*)&pw[lc * P_LD + kc * 32 + lr * 8];
                bf16x8 vf = *(const bf16x8*)&Vsh[(dn * 16 + lc) * V_LD + kc * 32 + lr * 8];
                o = __builtin_amdgcn_mfma_f32_16x16x32_bf16(pf, vf, o, 0, 0, 0);
            }
            acc[dn] = o;
        }
    }

    float* op = out + (size_t)(r * BLK + w * 16) * ROWSTRIDE + h * DIMD;
    #pragma unroll
    for (int rr = 0; rr < 4; ++rr) {
        float inv = 1.0f / l_run[rr];
        float* orow = op + (size_t)(lr * 4 + rr) * ROWSTRIDE;
        #pragma unroll
        for (int dn = 0; dn < 4; ++dn) {
            orow[dn * 16 + lc] = acc[dn][rr] * inv;
        }
    }
}

extern "C" void kernel_launch(void* const* d_in, const int* in_sizes, int n_in,
                              void* d_out, int out_size, void* d_ws, size_t ws_size,
                              hipStream_t stream) {
    const float* q = (const float*)d_in[0];
    const float* k = (const float*)d_in[1];
    const float* v = (const float*)d_in[2];
    float* out = (float*)d_out;

    if (ws_size >= (size_t)WS_NEEDED) {
        short* Kb = (short*)d_ws;
        short* Vt = Kb + (size_t)NH * HEAD_ELEMS;
        prep_kernel<<<1280, 256, 0, stream>>>(k, v, Kb, Vt);
        bsattn_main<<<dim3(NROW * 2, NH), 256, 0, stream>>>(q, Kb, Vt, out);
    } else {
        bsattn_fallback<<<dim3(NROW, NH), 512, 0, stream>>>(q, k, v, out);
    }
}

// Round 4
// 42.902 us; speedup vs baseline: 1.5048x; 1.0365x over previous
//
#include <hip/hip_runtime.h>
#include <hip/hip_bf16.h>

#define NATOM 4096
#define NH 8
#define DIMD 64
#define BLK 128
#define NROW 32
#define BPS 4
#define ROWSTRIDE (NH * DIMD)   // 512 floats
#define SCALE 0.125f
#define L2E 1.4426950408889634f

#define K_LD 72     // [128][72] shorts, row stride 144B
#define V_LD 136    // [64][136] shorts (transposed+permuted V)
#define P_LD 136    // fallback only

#define HEAD_ELEMS (NATOM * DIMD)               // 262144 bf16 per head plane
#define WS_NEEDED  (2u * NH * HEAD_ELEMS * 2u)  // Kb + Vt, bf16

typedef __attribute__((ext_vector_type(8))) short bf16x8;
typedef __attribute__((ext_vector_type(4))) float f32x4;

__device__ __forceinline__ short f2bf(float x) {
    unsigned int u = __builtin_bit_cast(unsigned int, x);
    unsigned int r = (u + 0x7fffu + ((u >> 16) & 1u)) >> 16;
    return (short)r;
}
__device__ __forceinline__ f32x4 vmax4(f32x4 a, f32x4 b) {
    f32x4 r;
    r[0] = fmaxf(a[0], b[0]); r[1] = fmaxf(a[1], b[1]);
    r[2] = fmaxf(a[2], b[2]); r[3] = fmaxf(a[3], b[3]);
    return r;
}

// ---------------- prep kernel: K -> bf16 [h][n][d]; V -> bf16 [h][d][perm(n)] ----------------
// V column permutation within each 128-key block: column c = kc*32 + lr*8 + j
// holds key kappa(c) = kc*32 + (j>>2)*16 + lr*4 + (j&3). This makes PV's
// B-fragment lane-local to the QK^T S-fragment (no P transpose needed).
extern "C" __global__ __launch_bounds__(256)
void prep_kernel(const float* __restrict__ k, const float* __restrict__ v,
                 short* __restrict__ Kb, short* __restrict__ Vt)
{
    __shared__ short Tr[DIMD * V_LD];
    const int b = blockIdx.x;
    const int t = threadIdx.x;
    if (b < 1024) {
        // K convert: 262144 slots of 8 elems
        int tid = b * 256 + t;
        int h   = tid >> 15;
        int rem = tid & 32767;
        int n   = rem >> 3;
        int d0  = (rem & 7) * 8;
        const float* src = k + (size_t)n * ROWSTRIDE + h * DIMD + d0;
        float4 a = *(const float4*)src;
        float4 c = *(const float4*)(src + 4);
        bf16x8 f;
        f[0] = f2bf(a.x); f[1] = f2bf(a.y); f[2] = f2bf(a.z); f[3] = f2bf(a.w);
        f[4] = f2bf(c.x); f[5] = f2bf(c.y); f[6] = f2bf(c.z); f[7] = f2bf(c.w);
        *(bf16x8*)(Kb + (size_t)h * HEAD_ELEMS + (size_t)n * DIMD + d0) = f;
    } else {
        // V transpose+permute: 256 tiles (nb, h)
        int bb = b - 1024;
        int nb = bb & 31;
        int h  = bb >> 5;
        const int vd = t & 63;
        const int g  = t >> 6;
        const float* vp = v + (size_t)(nb * BLK) * ROWSTRIDE + h * DIMD + vd;
        #pragma unroll
        for (int i = 0; i < 8; ++i) {
            int n4 = i * 16 + g * 4;
            const float* vr = vp + (size_t)n4 * ROWSTRIDE;
            short4 s4;
            s4.x = f2bf(vr[0 * ROWSTRIDE]);
            s4.y = f2bf(vr[1 * ROWSTRIDE]);
            s4.z = f2bf(vr[2 * ROWSTRIDE]);
            s4.w = f2bf(vr[3 * ROWSTRIDE]);
            *(short4*)&Tr[vd * V_LD + n4] = s4;   // Tr column = natural local key
        }
        __syncthreads();
        #pragma unroll
        for (int i = 0; i < 4; ++i) {
            int s  = i * 256 + t;
            int d  = s >> 4;
            int c8 = (s & 15) * 8;                 // output column block (perm applied)
            int kc = c8 >> 5;
            int l2 = (c8 >> 3) & 3;
            int kA = kc * 32 + l2 * 4;             // keys for j=0..3
            short4 a = *(const short4*)&Tr[d * V_LD + kA];
            short4 c4 = *(const short4*)&Tr[d * V_LD + kA + 16];  // keys for j=4..7
            bf16x8 f;
            f[0] = a.x;  f[1] = a.y;  f[2] = a.z;  f[3] = a.w;
            f[4] = c4.x; f[5] = c4.y; f[6] = c4.z; f[7] = c4.w;
            *(bf16x8*)(Vt + (size_t)h * HEAD_ELEMS + (size_t)d * NATOM + nb * BLK + c8) = f;
        }
    }
}

// ---------------- main kernel: swapped-operand flash attn, dbuf LDS, 1 barrier/iter ----------------
// S^T = mfma(K,Q): lane holds S[key = mt*16 + lr*4 + e][q = lc]
// PV: pf[kc] = {s[2kc][0..3], s[2kc+1][0..3]} lane-local (V columns pre-permuted)
// O^T = mfma(Vt,P): lane holds O[q = lc][d = dn*16 + lr*4 + reg]
extern "C" __global__ __launch_bounds__(256)
void bsattn_main(const float* __restrict__ q,
                 const short* __restrict__ Kb,
                 const short* __restrict__ Vt,
                 float* __restrict__ out)
{
    __shared__ short Ksh[2][BLK * K_LD];
    __shared__ short Vsh[2][DIMD * V_LD];

    const int br = blockIdx.x;        // 64-row query block, 0..63
    const int h  = blockIdx.y;
    const int r  = br >> 1;           // 128-row band block
    const int t  = threadIdx.x;
    const int w  = t >> 6;
    const int lane = t & 63;
    const int lr = lane >> 4;
    const int lc = lane & 15;

    // ---- Q fragments (scale folded); B-layout: q = lc, d = kc*32 + lr*8 + j ----
    const int qbase = br * 64 + w * 16;
    const float* qp = q + (size_t)(qbase + lc) * ROWSTRIDE + h * DIMD + lr * 8;
    bf16x8 qf[2];
    #pragma unroll
    for (int kc = 0; kc < 2; ++kc) {
        float4 a = *(const float4*)(qp + kc * 32);
        float4 b = *(const float4*)(qp + kc * 32 + 4);
        bf16x8 f;
        f[0] = f2bf(a.x * SCALE); f[1] = f2bf(a.y * SCALE);
        f[2] = f2bf(a.z * SCALE); f[3] = f2bf(a.w * SCALE);
        f[4] = f2bf(b.x * SCALE); f[5] = f2bf(b.y * SCALE);
        f[6] = f2bf(b.z * SCALE); f[7] = f2bf(b.w * SCALE);
        qf[kc] = f;
    }

    const short* kbase = Kb + (size_t)h * HEAD_ELEMS;
    const short* vbase = Vt + (size_t)h * HEAD_ELEMS;

    f32x4 acc[4] = {};
    float m_run = -1e30f, l_run = 0.0f;

    const int kb0 = (r - BPS > 0) ? (r - BPS) : 0;
    const int kb1 = (r + BPS < NROW - 1) ? (r + BPS) : (NROW - 1);

    const short* kg = kbase + (size_t)kb0 * BLK * DIMD;
    const short* vg = vbase + (size_t)kb0 * BLK;
    bf16x8 kpre[4], vpre[4];

#define LOADREGS()                                                              \
    {                                                                           \
        _Pragma("unroll")                                                       \
        for (int i = 0; i < 4; ++i) {                                           \
            int s = i * 256 + t;                                                \
            kpre[i] = *(const bf16x8*)(kg + (size_t)(s >> 3) * DIMD + (s & 7) * 8); \
            vpre[i] = *(const bf16x8*)(vg + (size_t)(s >> 4) * NATOM + (s & 15) * 8); \
        }                                                                       \
        kg += BLK * DIMD; vg += BLK;                                            \
    }

#define STAGE(buf)                                                              \
    {                                                                           \
        _Pragma("unroll")                                                       \
        for (int i = 0; i < 4; ++i) {                                           \
            int s = i * 256 + t;                                                \
            *(bf16x8*)&Ksh[buf][(s >> 3) * K_LD + (s & 7) * 8] = kpre[i];       \
            *(bf16x8*)&Vsh[buf][(s >> 4) * V_LD + (s & 15) * 8] = vpre[i];      \
        }                                                                       \
    }

    LOADREGS();           // tile kb0
    STAGE(0);
    if (kb0 < kb1) LOADREGS();   // tile kb0+1 in flight
    __syncthreads();

    int cur = 0;
    for (int kb = kb0; kb <= kb1; ++kb) {
        const short* ks = &Ksh[cur][0];
        const short* vs = &Vsh[cur][0];

        // ---- S^T = K (Q*scale)^T ----
        f32x4 s[8];
        __builtin_amdgcn_s_setprio(1);
        #pragma unroll
        for (int mt = 0; mt < 8; ++mt) {
            f32x4 z = {};
            #pragma unroll
            for (int kc = 0; kc < 2; ++kc) {
                bf16x8 kf = *(const bf16x8*)&ks[(mt * 16 + lc) * K_LD + kc * 32 + lr * 8];
                z = __builtin_amdgcn_mfma_f32_16x16x32_bf16(kf, qf[kc], z, 0, 0, 0);
            }
            s[mt] = z;
        }
        __builtin_amdgcn_s_setprio(0);

        // ---- online softmax: keys lane-local; defer-max (THR=8) ----
        f32x4 a0 = vmax4(vmax4(s[0], s[1]), vmax4(s[2], s[3]));
        f32x4 a1 = vmax4(vmax4(s[4], s[5]), vmax4(s[6], s[7]));
        a0 = vmax4(a0, a1);
        float mx = fmaxf(fmaxf(a0[0], a0[1]), fmaxf(a0[2], a0[3]));
        mx = fmaxf(mx, __shfl_xor(mx, 16, 64));
        mx = fmaxf(mx, __shfl_xor(mx, 32, 64));
        if (__any(mx > m_run + 8.0f)) {
            float mnew = fmaxf(m_run, mx);
            float al = exp2f((m_run - mnew) * L2E);
            m_run = mnew;
            l_run *= al;
            #pragma unroll
            for (int dn = 0; dn < 4; ++dn) {
                acc[dn][0] *= al; acc[dn][1] *= al;
                acc[dn][2] *= al; acc[dn][3] *= al;
            }
        }
        f32x4 sv = {};
        #pragma unroll
        for (int mt = 0; mt < 8; ++mt) {
            #pragma unroll
            for (int e = 0; e < 4; ++e) {
                float p = exp2f((s[mt][e] - m_run) * L2E);
                s[mt][e] = p;
                sv[e] += p;
            }
        }
        float sum = (sv[0] + sv[1]) + (sv[2] + sv[3]);
        sum += __shfl_xor(sum, 16, 64);
        sum += __shfl_xor(sum, 32, 64);
        l_run += sum;

        // ---- pf: lane-local pack (V columns pre-permuted) ----
        bf16x8 pf[4];
        #pragma unroll
        for (int kc = 0; kc < 4; ++kc) {
            bf16x8 f;
            f[0] = f2bf(s[2 * kc][0]);     f[1] = f2bf(s[2 * kc][1]);
            f[2] = f2bf(s[2 * kc][2]);     f[3] = f2bf(s[2 * kc][3]);
            f[4] = f2bf(s[2 * kc + 1][0]); f[5] = f2bf(s[2 * kc + 1][1]);
            f[6] = f2bf(s[2 * kc + 1][2]); f[7] = f2bf(s[2 * kc + 1][3]);
            pf[kc] = f;
        }

        // ---- O^T += Vt P ----
        __builtin_amdgcn_s_setprio(1);
        #pragma unroll
        for (int dn = 0; dn < 4; ++dn) {
            f32x4 o = acc[dn];
            #pragma unroll
            for (int kc = 0; kc < 4; ++kc) {
                bf16x8 vf = *(const bf16x8*)&vs[(dn * 16 + lc) * V_LD + kc * 32 + lr * 8];
                o = __builtin_amdgcn_mfma_f32_16x16x32_bf16(vf, pf[kc], o, 0, 0, 0);
            }
            acc[dn] = o;
        }
        __builtin_amdgcn_s_setprio(0);

        // ---- stage next tile into the other buffer; prefetch tile after ----
        if (kb < kb1) {
            STAGE(cur ^ 1);
            if (kb + 1 < kb1) LOADREGS();
        }
        __syncthreads();
        cur ^= 1;
    }

    // ---- epilogue: q = lc, d = dn*16 + lr*4 + reg -> float4 stores ----
    float inv = 1.0f / l_run;
    float* orow = out + (size_t)(qbase + lc) * ROWSTRIDE + h * DIMD;
    #pragma unroll
    for (int dn = 0; dn < 4; ++dn) {
        f32x4 rv;
        rv[0] = acc[dn][0] * inv; rv[1] = acc[dn][1] * inv;
        rv[2] = acc[dn][2] * inv; rv[3] = acc[dn][3] * inv;
        *(float4*)(orow + dn * 16 + lr * 4) = *(float4*)&rv;
    }
#undef LOADREGS
#undef STAGE
}

// ---------------- fallback (fp32 direct, round-1 proven) ----------------
extern "C" __global__ __launch_bounds__(512)
void bsattn_fallback(const float* __restrict__ q,
                     const float* __restrict__ k,
                     const float* __restrict__ v,
                     float* __restrict__ out)
{
    __shared__ short Ksh[BLK * K_LD];
    __shared__ short Vsh[DIMD * V_LD];
    __shared__ short Psh[8][16 * P_LD];

    const int r = blockIdx.x;
    const int h = blockIdx.y;
    const int t = threadIdx.x;
    const int w = t >> 6;
    const int lane = t & 63;
    const int lr = lane >> 4;
    const int lc = lane & 15;

    const int krow = t >> 4;
    const int kcol = (t & 15) * 4;
    const int vd  = t & 63;
    const int vkg = t >> 6;

    const int qrow_l = w * 16 + lc;
    const float* qp = q + (size_t)(r * BLK + qrow_l) * ROWSTRIDE + h * DIMD + lr * 8;
    bf16x8 qf[2];
    #pragma unroll
    for (int kc = 0; kc < 2; ++kc) {
        float4 a = *(const float4*)(qp + kc * 32);
        float4 b = *(const float4*)(qp + kc * 32 + 4);
        bf16x8 f;
        f[0] = f2bf(a.x); f[1] = f2bf(a.y); f[2] = f2bf(a.z); f[3] = f2bf(a.w);
        f[4] = f2bf(b.x); f[5] = f2bf(b.y); f[6] = f2bf(b.z); f[7] = f2bf(b.w);
        qf[kc] = f;
    }

    f32x4 acc[4] = {};
    float m_run[4], l_run[4];
    #pragma unroll
    for (int i = 0; i < 4; ++i) { m_run[i] = -1e30f; l_run[i] = 0.0f; }

    const int kb0 = (r - BPS > 0) ? (r - BPS) : 0;
    const int kb1 = (r + BPS < NROW - 1) ? (r + BPS) : (NROW - 1);

    for (int kb = kb0; kb <= kb1; ++kb) {
        __syncthreads();
        const float* kp = k + (size_t)(kb * BLK) * ROWSTRIDE + h * DIMD;
        const float* vp = v + (size_t)(kb * BLK) * ROWSTRIDE + h * DIMD;

        #pragma unroll
        for (int i = 0; i < 4; ++i) {
            float4 kv = *(const float4*)(kp + (size_t)(i * 32 + krow) * ROWSTRIDE + kcol);
            short4 ks;
            ks.x = f2bf(kv.x); ks.y = f2bf(kv.y); ks.z = f2bf(kv.z); ks.w = f2bf(kv.w);
            *(short4*)&Ksh[(i * 32 + krow) * K_LD + kcol] = ks;

            const float* vr = vp + (size_t)(i * 32 + vkg * 4) * ROWSTRIDE + vd;
            short4 vs;
            vs.x = f2bf(vr[0 * ROWSTRIDE]);
            vs.y = f2bf(vr[1 * ROWSTRIDE]);
            vs.z = f2bf(vr[2 * ROWSTRIDE]);
            vs.w = f2bf(vr[3 * ROWSTRIDE]);
            *(short4*)&Vsh[vd * V_LD + i * 32 + vkg * 4] = vs;
        }
        __syncthreads();

        f32x4 s[8];
        #pragma unroll
        for (int n = 0; n < 8; ++n) {
            f32x4 z = {};
            #pragma unroll
            for (int kc = 0; kc < 2; ++kc) {
                bf16x8 kf = *(const bf16x8*)&Ksh[(n * 16 + lc) * K_LD + kc * 32 + lr * 8];
                z = __builtin_amdgcn_mfma_f32_16x16x32_bf16(qf[kc], kf, z, 0, 0, 0);
            }
            s[n] = z * SCALE;
        }

        #pragma unroll
        for (int rr = 0; rr < 4; ++rr) {
            float mx = s[0][rr];
            #pragma unroll
            for (int n = 1; n < 8; ++n) mx = fmaxf(mx, s[n][rr]);
            #pragma unroll
            for (int off = 1; off < 16; off <<= 1)
                mx = fmaxf(mx, __shfl_xor(mx, off, 64));
            float mnew = fmaxf(m_run[rr], mx);
            float al = exp2f((m_run[rr] - mnew) * L2E);
            m_run[rr] = mnew;
            float sum = 0.0f;
            #pragma unroll
            for (int n = 0; n < 8; ++n) {
                float p = exp2f((s[n][rr] - mnew) * L2E);
                s[n][rr] = p;
                sum += p;
            }
            #pragma unroll
            for (int off = 1; off < 16; off <<= 1)
                sum += __shfl_xor(sum, off, 64);
            l_run[rr] = l_run[rr] * al + sum;
            #pragma unroll
            for (int dn = 0; dn < 4; ++dn) acc[dn][rr] *= al;
        }

        short* pw = &Psh[w][0];
        #pragma unroll
        for (int n = 0; n < 8; ++n) {
            #pragma unroll
            for (int rr = 0; rr < 4; ++rr) {
                pw[(lr * 4 + rr) * P_LD + n * 16 + lc] = f2bf(s[n][rr]);
            }
        }

        #pragma unroll
        for (int dn = 0; dn < 4; ++dn) {
            f32x4 o = acc[dn];
            #pragma unroll
            for (int kc = 0; kc < 4; ++kc) {
                bf16x8 pf = *(const bf16x8*)&pw[lc * P_LD + kc * 32 + lr * 8];
                bf16x8 vf = *(const bf16x8*)&Vsh[(dn * 16 + lc) * V_LD + kc * 32 + lr * 8];
                o = __builtin_amdgcn_mfma_f32_16x16x32_bf16(pf, vf, o, 0, 0, 0);
            }
            acc[dn] = o;
        }
    }

    float* op = out + (size_t)(r * BLK + w * 16) * ROWSTRIDE + h * DIMD;
    #pragma unroll
    for (int rr = 0; rr < 4; ++rr) {
        float inv = 1.0f / l_run[rr];
        float* orow = op + (size_t)(lr * 4 + rr) * ROWSTRIDE;
        #pragma unroll
        for (int dn = 0; dn < 4; ++dn) {
            orow[dn * 16 + lc] = acc[dn][rr] * inv;
        }
    }
}

extern "C" void kernel_launch(void* const* d_in, const int* in_sizes, int n_in,
                              void* d_out, int out_size, void* d_ws, size_t ws_size,
                              hipStream_t stream) {
    const float* q = (const float*)d_in[0];
    const float* k = (const float*)d_in[1];
    const float* v = (const float*)d_in[2];
    float* out = (float*)d_out;

    if (ws_size >= (size_t)WS_NEEDED) {
        short* Kb = (short*)d_ws;
        short* Vt = Kb + (size_t)NH * HEAD_ELEMS;
        prep_kernel<<<1280, 256, 0, stream>>>(k, v, Kb, Vt);
        bsattn_main<<<dim3(NROW * 2, NH), 256, 0, stream>>>(q, Kb, Vt, out);
    } else {
        bsattn_fallback<<<dim3(NROW, NH), 512, 0, stream>>>(q, k, v, out);
    }
}

// Round 5
// 33.097 us; speedup vs baseline: 1.9505x; 1.2963x over previous
//
#include <hip/hip_runtime.h>
#include <hip/hip_bf16.h>

#define NATOM 4096
#define NH 8
#define DIMD 64
#define BLK 128
#define NROW 32
#define BPS 4
#define ROWSTRIDE (NH * DIMD)   // 512 floats
#define SCALE 0.125f
#define L2E 1.4426950408889634f

#define K_LD 72     // [128][72] shorts, row stride 144B
#define V_LD 136    // [64][136] shorts (transposed+permuted V)
#define P_LD 136    // fallback only

#define HEAD_ELEMS (NATOM * DIMD)               // 262144 bf16 per head plane
#define WS_NEEDED  (2u * NH * HEAD_ELEMS * 2u)  // Kb + Vt, bf16

typedef __attribute__((ext_vector_type(8))) short bf16x8;
typedef __attribute__((ext_vector_type(4))) float f32x4;
typedef __attribute__((ext_vector_type(4))) unsigned int u32x4;

__device__ __forceinline__ short f2bf(float x) {
    unsigned int u = __builtin_bit_cast(unsigned int, x);
    unsigned int r = (u + 0x7fffu + ((u >> 16) & 1u)) >> 16;
    return (short)r;
}
__device__ __forceinline__ unsigned int cvtpk(float lo, float hi) {
    unsigned int r;
    asm("v_cvt_pk_bf16_f32 %0, %1, %2" : "=v"(r) : "v"(lo), "v"(hi));
    return r;
}
__device__ __forceinline__ f32x4 vmax4(f32x4 a, f32x4 b) {
    f32x4 r;
    r[0] = fmaxf(a[0], b[0]); r[1] = fmaxf(a[1], b[1]);
    r[2] = fmaxf(a[2], b[2]); r[3] = fmaxf(a[3], b[3]);
    return r;
}

// ---------------- prep kernel: 512 blocks, h-major XCD swizzle ----------------
// h = bid & 7 -> all of head h's work on XCD (h) under round-robin dispatch;
// Kb/Vt written into the same XCD's L2 that the main kernel will read from.
// K -> bf16 [h][n][d]; V -> bf16 [h][d][perm(n)] where within each 128-key
// block, column c = kc*32 + lr*8 + j holds key kc*32 + (j>>2)*16 + lr*4 + (j&3)
// (makes PV's B-fragment lane-local to the QK^T S-fragment).
extern "C" __global__ __launch_bounds__(256)
void prep_kernel(const float* __restrict__ k, const float* __restrict__ v,
                 short* __restrict__ Kb, short* __restrict__ Vt)
{
    __shared__ short Tr[DIMD * V_LD];
    const int bid  = blockIdx.x;
    const int h    = bid & 7;
    const int part = bid >> 3;          // 0..63
    const int t    = threadIdx.x;

    if (part < 32) {
        // K convert: tile nb = part (128 rows x 64 d), 4 x bf16x8 per thread
        const int nb = part;
        #pragma unroll
        for (int i = 0; i < 4; ++i) {
            int idx = i * 256 + t;          // 0..1023
            int row = idx >> 3;             // 0..127
            int d0  = (idx & 7) * 8;
            const float* src = k + (size_t)(nb * BLK + row) * ROWSTRIDE + h * DIMD + d0;
            float4 a = *(const float4*)src;
            float4 c = *(const float4*)(src + 4);
            bf16x8 f;
            f[0] = f2bf(a.x); f[1] = f2bf(a.y); f[2] = f2bf(a.z); f[3] = f2bf(a.w);
            f[4] = f2bf(c.x); f[5] = f2bf(c.y); f[6] = f2bf(c.z); f[7] = f2bf(c.w);
            *(bf16x8*)(Kb + (size_t)h * HEAD_ELEMS + (size_t)(nb * BLK + row) * DIMD + d0) = f;
        }
    } else {
        // V transpose+permute: tile nb = part - 32
        const int nb = part - 32;
        const int vd = t & 63;
        const int g  = t >> 6;
        const float* vp = v + (size_t)(nb * BLK) * ROWSTRIDE + h * DIMD + vd;
        #pragma unroll
        for (int i = 0; i < 8; ++i) {
            int n4 = i * 16 + g * 4;
            const float* vr = vp + (size_t)n4 * ROWSTRIDE;
            short4 s4;
            s4.x = f2bf(vr[0 * ROWSTRIDE]);
            s4.y = f2bf(vr[1 * ROWSTRIDE]);
            s4.z = f2bf(vr[2 * ROWSTRIDE]);
            s4.w = f2bf(vr[3 * ROWSTRIDE]);
            *(short4*)&Tr[vd * V_LD + n4] = s4;   // Tr column = natural local key
        }
        __syncthreads();
        #pragma unroll
        for (int i = 0; i < 4; ++i) {
            int s  = i * 256 + t;
            int d  = s >> 4;
            int c8 = (s & 15) * 8;                 // output column block (perm applied)
            int kc = c8 >> 5;
            int l2 = (c8 >> 3) & 3;
            int kA = kc * 32 + l2 * 4;             // keys for j=0..3
            short4 a  = *(const short4*)&Tr[d * V_LD + kA];
            short4 c4 = *(const short4*)&Tr[d * V_LD + kA + 16];  // keys for j=4..7
            bf16x8 f;
            f[0] = a.x;  f[1] = a.y;  f[2] = a.z;  f[3] = a.w;
            f[4] = c4.x; f[5] = c4.y; f[6] = c4.z; f[7] = c4.w;
            *(bf16x8*)(Vt + (size_t)h * HEAD_ELEMS + (size_t)d * NATOM + nb * BLK + c8) = f;
        }
    }
}

// ---------------- main kernel: swapped-operand flash attn, dbuf LDS, 1 barrier/iter ----------------
// 1-D grid 512, h = bid & 7 (same XCD as the prep blocks that produced this head).
// S^T = mfma(K,Q): lane holds S[key = mt*16 + lr*4 + e][q = lc]
// PV: pf[kc] = {s[2kc][0..3], s[2kc+1][0..3]} lane-local (V columns pre-permuted)
// O^T = mfma(Vt,P): lane holds O[q = lc][d = dn*16 + lr*4 + reg]
extern "C" __global__ __launch_bounds__(256)
void bsattn_main(const float* __restrict__ q,
                 const short* __restrict__ Kb,
                 const short* __restrict__ Vt,
                 float* __restrict__ out)
{
    __shared__ short Ksh[2][BLK * K_LD];
    __shared__ short Vsh[2][DIMD * V_LD];

    const int bid = blockIdx.x;
    const int h   = bid & 7;
    const int br  = bid >> 3;         // 64-row query block, 0..63
    const int r   = br >> 1;          // 128-row band block
    const int t   = threadIdx.x;
    const int w   = t >> 6;
    const int lane = t & 63;
    const int lr = lane >> 4;
    const int lc = lane & 15;

    // ---- Q fragments (scale folded); B-layout: q = lc, d = kc*32 + lr*8 + j ----
    const int qbase = br * 64 + w * 16;
    const float* qp = q + (size_t)(qbase + lc) * ROWSTRIDE + h * DIMD + lr * 8;
    bf16x8 qf[2];
    #pragma unroll
    for (int kc = 0; kc < 2; ++kc) {
        float4 a = *(const float4*)(qp + kc * 32);
        float4 b = *(const float4*)(qp + kc * 32 + 4);
        bf16x8 f;
        f[0] = f2bf(a.x * SCALE); f[1] = f2bf(a.y * SCALE);
        f[2] = f2bf(a.z * SCALE); f[3] = f2bf(a.w * SCALE);
        f[4] = f2bf(b.x * SCALE); f[5] = f2bf(b.y * SCALE);
        f[6] = f2bf(b.z * SCALE); f[7] = f2bf(b.w * SCALE);
        qf[kc] = f;
    }

    const short* kbase = Kb + (size_t)h * HEAD_ELEMS;
    const short* vbase = Vt + (size_t)h * HEAD_ELEMS;

    f32x4 acc[4] = {};
    float m_run = -1e30f, l_run = 0.0f;

    const int kb0 = (r - BPS > 0) ? (r - BPS) : 0;
    const int kb1 = (r + BPS < NROW - 1) ? (r + BPS) : (NROW - 1);

    const short* kg = kbase + (size_t)kb0 * BLK * DIMD;
    const short* vg = vbase + (size_t)kb0 * BLK;
    bf16x8 kpre[4], vpre[4];

#define LOADREGS()                                                              \
    {                                                                           \
        _Pragma("unroll")                                                       \
        for (int i = 0; i < 4; ++i) {                                           \
            int s = i * 256 + t;                                                \
            kpre[i] = *(const bf16x8*)(kg + (size_t)(s >> 3) * DIMD + (s & 7) * 8); \
            vpre[i] = *(const bf16x8*)(vg + (size_t)(s >> 4) * NATOM + (s & 15) * 8); \
        }                                                                       \
        kg += BLK * DIMD; vg += BLK;                                            \
    }

#define STAGE(buf)                                                              \
    {                                                                           \
        _Pragma("unroll")                                                       \
        for (int i = 0; i < 4; ++i) {                                           \
            int s = i * 256 + t;                                                \
            *(bf16x8*)&Ksh[buf][(s >> 3) * K_LD + (s & 7) * 8] = kpre[i];       \
            *(bf16x8*)&Vsh[buf][(s >> 4) * V_LD + (s & 15) * 8] = vpre[i];      \
        }                                                                       \
    }

    LOADREGS();           // tile kb0
    STAGE(0);
    if (kb0 < kb1) LOADREGS();   // tile kb0+1 in flight
    __syncthreads();

    int cur = 0;
    for (int kb = kb0; kb <= kb1; ++kb) {
        const short* ks = &Ksh[cur][0];
        const short* vs = &Vsh[cur][0];

        // ---- S^T = K (Q*scale)^T ----
        f32x4 s[8];
        __builtin_amdgcn_s_setprio(1);
        #pragma unroll
        for (int mt = 0; mt < 8; ++mt) {
            f32x4 z = {};
            #pragma unroll
            for (int kc = 0; kc < 2; ++kc) {
                bf16x8 kf = *(const bf16x8*)&ks[(mt * 16 + lc) * K_LD + kc * 32 + lr * 8];
                z = __builtin_amdgcn_mfma_f32_16x16x32_bf16(kf, qf[kc], z, 0, 0, 0);
            }
            s[mt] = z;
        }
        __builtin_amdgcn_s_setprio(0);

        // ---- online softmax: keys lane-local; defer-max (THR=8) ----
        f32x4 a0 = vmax4(vmax4(s[0], s[1]), vmax4(s[2], s[3]));
        f32x4 a1 = vmax4(vmax4(s[4], s[5]), vmax4(s[6], s[7]));
        a0 = vmax4(a0, a1);
        float mx = fmaxf(fmaxf(a0[0], a0[1]), fmaxf(a0[2], a0[3]));
        mx = fmaxf(mx, __shfl_xor(mx, 16, 64));
        mx = fmaxf(mx, __shfl_xor(mx, 32, 64));
        if (__any(mx > m_run + 8.0f)) {
            float mnew = fmaxf(m_run, mx);
            float al = __builtin_amdgcn_exp2f((m_run - mnew) * L2E);
            m_run = mnew;
            l_run *= al;
            #pragma unroll
            for (int dn = 0; dn < 4; ++dn) {
                acc[dn][0] *= al; acc[dn][1] *= al;
                acc[dn][2] *= al; acc[dn][3] *= al;
            }
        }
        f32x4 sv = {};
        #pragma unroll
        for (int mt = 0; mt < 8; ++mt) {
            #pragma unroll
            for (int e = 0; e < 4; ++e) {
                float p = __builtin_amdgcn_exp2f((s[mt][e] - m_run) * L2E);
                s[mt][e] = p;
                sv[e] += p;
            }
        }
        float sum = (sv[0] + sv[1]) + (sv[2] + sv[3]);
        sum += __shfl_xor(sum, 16, 64);
        sum += __shfl_xor(sum, 32, 64);
        l_run += sum;

        // ---- pf: lane-local pack via v_cvt_pk_bf16_f32 (V columns pre-permuted) ----
        bf16x8 pf[4];
        #pragma unroll
        for (int kc = 0; kc < 4; ++kc) {
            u32x4 pk;
            pk[0] = cvtpk(s[2 * kc][0],     s[2 * kc][1]);
            pk[1] = cvtpk(s[2 * kc][2],     s[2 * kc][3]);
            pk[2] = cvtpk(s[2 * kc + 1][0], s[2 * kc + 1][1]);
            pk[3] = cvtpk(s[2 * kc + 1][2], s[2 * kc + 1][3]);
            pf[kc] = __builtin_bit_cast(bf16x8, pk);
        }

        // ---- O^T += Vt P ----
        __builtin_amdgcn_s_setprio(1);
        #pragma unroll
        for (int dn = 0; dn < 4; ++dn) {
            f32x4 o = acc[dn];
            #pragma unroll
            for (int kc = 0; kc < 4; ++kc) {
                bf16x8 vf = *(const bf16x8*)&vs[(dn * 16 + lc) * V_LD + kc * 32 + lr * 8];
                o = __builtin_amdgcn_mfma_f32_16x16x32_bf16(vf, pf[kc], o, 0, 0, 0);
            }
            acc[dn] = o;
        }
        __builtin_amdgcn_s_setprio(0);

        // ---- stage next tile into the other buffer; prefetch tile after ----
        if (kb < kb1) {
            STAGE(cur ^ 1);
            if (kb + 1 < kb1) LOADREGS();
        }
        __syncthreads();
        cur ^= 1;
    }

    // ---- epilogue: q = lc, d = dn*16 + lr*4 + reg -> float4 stores ----
    float inv = 1.0f / l_run;
    float* orow = out + (size_t)(qbase + lc) * ROWSTRIDE + h * DIMD;
    #pragma unroll
    for (int dn = 0; dn < 4; ++dn) {
        f32x4 rv;
        rv[0] = acc[dn][0] * inv; rv[1] = acc[dn][1] * inv;
        rv[2] = acc[dn][2] * inv; rv[3] = acc[dn][3] * inv;
        *(float4*)(orow + dn * 16 + lr * 4) = *(float4*)&rv;
    }
#undef LOADREGS
#undef STAGE
}

// ---------------- fallback (fp32 direct, round-1 proven) ----------------
extern "C" __global__ __launch_bounds__(512)
void bsattn_fallback(const float* __restrict__ q,
                     const float* __restrict__ k,
                     const float* __restrict__ v,
                     float* __restrict__ out)
{
    __shared__ short Ksh[BLK * K_LD];
    __shared__ short Vsh[DIMD * V_LD];
    __shared__ short Psh[8][16 * P_LD];

    const int r = blockIdx.x;
    const int h = blockIdx.y;
    const int t = threadIdx.x;
    const int w = t >> 6;
    const int lane = t & 63;
    const int lr = lane >> 4;
    const int lc = lane & 15;

    const int krow = t >> 4;
    const int kcol = (t & 15) * 4;
    const int vd  = t & 63;
    const int vkg = t >> 6;

    const int qrow_l = w * 16 + lc;
    const float* qp = q + (size_t)(r * BLK + qrow_l) * ROWSTRIDE + h * DIMD + lr * 8;
    bf16x8 qf[2];
    #pragma unroll
    for (int kc = 0; kc < 2; ++kc) {
        float4 a = *(const float4*)(qp + kc * 32);
        float4 b = *(const float4*)(qp + kc * 32 + 4);
        bf16x8 f;
        f[0] = f2bf(a.x); f[1] = f2bf(a.y); f[2] = f2bf(a.z); f[3] = f2bf(a.w);
        f[4] = f2bf(b.x); f[5] = f2bf(b.y); f[6] = f2bf(b.z); f[7] = f2bf(b.w);
        qf[kc] = f;
    }

    f32x4 acc[4] = {};
    float m_run[4], l_run[4];
    #pragma unroll
    for (int i = 0; i < 4; ++i) { m_run[i] = -1e30f; l_run[i] = 0.0f; }

    const int kb0 = (r - BPS > 0) ? (r - BPS) : 0;
    const int kb1 = (r + BPS < NROW - 1) ? (r + BPS) : (NROW - 1);

    for (int kb = kb0; kb <= kb1; ++kb) {
        __syncthreads();
        const float* kp = k + (size_t)(kb * BLK) * ROWSTRIDE + h * DIMD;
        const float* vp = v + (size_t)(kb * BLK) * ROWSTRIDE + h * DIMD;

        #pragma unroll
        for (int i = 0; i < 4; ++i) {
            float4 kv = *(const float4*)(kp + (size_t)(i * 32 + krow) * ROWSTRIDE + kcol);
            short4 ks;
            ks.x = f2bf(kv.x); ks.y = f2bf(kv.y); ks.z = f2bf(kv.z); ks.w = f2bf(kv.w);
            *(short4*)&Ksh[(i * 32 + krow) * K_LD + kcol] = ks;

            const float* vr = vp + (size_t)(i * 32 + vkg * 4) * ROWSTRIDE + vd;
            short4 vs;
            vs.x = f2bf(vr[0 * ROWSTRIDE]);
            vs.y = f2bf(vr[1 * ROWSTRIDE]);
            vs.z = f2bf(vr[2 * ROWSTRIDE]);
            vs.w = f2bf(vr[3 * ROWSTRIDE]);
            *(short4*)&Vsh[vd * V_LD + i * 32 + vkg * 4] = vs;
        }
        __syncthreads();

        f32x4 s[8];
        #pragma unroll
        for (int n = 0; n < 8; ++n) {
            f32x4 z = {};
            #pragma unroll
            for (int kc = 0; kc < 2; ++kc) {
                bf16x8 kf = *(const bf16x8*)&Ksh[(n * 16 + lc) * K_LD + kc * 32 + lr * 8];
                z = __builtin_amdgcn_mfma_f32_16x16x32_bf16(qf[kc], kf, z, 0, 0, 0);
            }
            s[n] = z * SCALE;
        }

        #pragma unroll
        for (int rr = 0; rr < 4; ++rr) {
            float mx = s[0][rr];
            #pragma unroll
            for (int n = 1; n < 8; ++n) mx = fmaxf(mx, s[n][rr]);
            #pragma unroll
            for (int off = 1; off < 16; off <<= 1)
                mx = fmaxf(mx, __shfl_xor(mx, off, 64));
            float mnew = fmaxf(m_run[rr], mx);
            float al = exp2f((m_run[rr] - mnew) * L2E);
            m_run[rr] = mnew;
            float sum = 0.0f;
            #pragma unroll
            for (int n = 0; n < 8; ++n) {
                float p = exp2f((s[n][rr] - mnew) * L2E);
                s[n][rr] = p;
                sum += p;
            }
            #pragma unroll
            for (int off = 1; off < 16; off <<= 1)
                sum += __shfl_xor(sum, off, 64);
            l_run[rr] = l_run[rr] * al + sum;
            #pragma unroll
            for (int dn = 0; dn < 4; ++dn) acc[dn][rr] *= al;
        }

        short* pw = &Psh[w][0];
        #pragma unroll
        for (int n = 0; n < 8; ++n) {
            #pragma unroll
            for (int rr = 0; rr < 4; ++rr) {
                pw[(lr * 4 + rr) * P_LD + n * 16 + lc] = f2bf(s[n][rr]);
            }
        }

        #pragma unroll
        for (int dn = 0; dn < 4; ++dn) {
            f32x4 o = acc[dn];
            #pragma unroll
            for (int kc = 0; kc < 4; ++kc) {
                bf16x8 pf = *(const bf16x8*)&pw[lc * P_LD + kc * 32 + lr * 8];
                bf16x8 vf = *(const bf16x8*)&Vsh[(dn * 16 + lc) * V_LD + kc * 32 + lr * 8];
                o = __builtin_amdgcn_mfma_f32_16x16x32_bf16(pf, vf, o, 0, 0, 0);
            }
            acc[dn] = o;
        }
    }

    float* op = out + (size_t)(r * BLK + w * 16) * ROWSTRIDE + h * DIMD;
    #pragma unroll
    for (int rr = 0; rr < 4; ++rr) {
        float inv = 1.0f / l_run[rr];
        float* orow = op + (size_t)(lr * 4 + rr) * ROWSTRIDE;
        #pragma unroll
        for (int dn = 0; dn < 4; ++dn) {
            orow[dn * 16 + lc] = acc[dn][rr] * inv;
        }
    }
}

extern "C" void kernel_launch(void* const* d_in, const int* in_sizes, int n_in,
                              void* d_out, int out_size, void* d_ws, size_t ws_size,
                              hipStream_t stream) {
    const float* q = (const float*)d_in[0];
    const float* k = (const float*)d_in[1];
    const float* v = (const float*)d_in[2];
    float* out = (float*)d_out;

    if (ws_size >= (size_t)WS_NEEDED) {
        short* Kb = (short*)d_ws;
        short* Vt = Kb + (size_t)NH * HEAD_ELEMS;
        prep_kernel<<<512, 256, 0, stream>>>(k, v, Kb, Vt);
        bsattn_main<<<512, 256, 0, stream>>>(q, Kb, Vt, out);
    } else {
        bsattn_fallback<<<dim3(NROW, NH), 512, 0, stream>>>(q, k, v, out);
    }
}